// Round 9
// baseline (730.070 us; speedup 1.0000x reference)
//
#include <hip/hip_runtime.h>
#include <stdint.h>

typedef short v8s __attribute__((ext_vector_type(8)));    // 8 bf16 (4 VGPRs)
typedef float v4f __attribute__((ext_vector_type(4)));    // 16x16 C/D frag
typedef float f32x16 __attribute__((ext_vector_type(16))); // 32x32 C/D frag

__device__ __forceinline__ unsigned short f2bf(float f) {
    union { float f; uint32_t u; } x; x.f = f;
    uint32_t r = (x.u + 0x7fffu + ((x.u >> 16) & 1u)) >> 16;
    return (unsigned short)r;
}
// packed f32x2 -> bf16x2 in one VALU op (gfx950 v_cvt_pk_bf16_f32, RNE)
__device__ __forceinline__ uint32_t cvt_pk_bf16(float lo, float hi) {
    uint32_t r;
    asm("v_cvt_pk_bf16_f32 %0, %1, %2" : "=v"(r) : "v"(lo), "v"(hi));
    return r;
}

#define QSCALE 0.18033688011112042f   /* 0.125 * log2(e) */
#define L2E    1.4426950408889634f    /* log2(e) — mask adds +1.0 to logits */

// ---------------- fp32 -> bf16 cast (memory-bound) ----------------
__global__ __launch_bounds__(256) void cast_f32_bf16(const float* __restrict__ in,
                                                     unsigned short* __restrict__ out, int n) {
    int i = (blockIdx.x * 256 + threadIdx.x) * 4;
    const int stride = gridDim.x * 256 * 4;
    for (; i < n; i += stride) {
        float4 v = *(const float4*)(in + i);
        ushort4 o;
        o.x = f2bf(v.x); o.y = f2bf(v.y); o.z = f2bf(v.z); o.w = f2bf(v.w);
        *(ushort4*)(out + i) = o;
    }
}

// ---------------- NT GEMM: C[M,N] = A[M,K] * B[N,K]^T + bias ----------------
// (unchanged from round 8 — proven; ~820 TF at QKV shape, m97-structure ceiling)
template <bool OUT_F32, bool VSPLIT>
__global__ __launch_bounds__(256) void gemm_nt(const unsigned short* __restrict__ A,
                                               const unsigned short* __restrict__ B,
                                               const float* __restrict__ bias,
                                               void* __restrict__ Cout,
                                               unsigned short* __restrict__ vt,
                                               int M, int N, int K, int ldc) {
    __shared__ unsigned short As[128 * 64];
    __shared__ unsigned short Bs[128 * 64];
    const int tid = threadIdx.x;
    const int wv = tid >> 6, lane = tid & 63;
    const int quad = lane >> 4, l16 = lane & 15;
    const int tiles_n = N >> 7;
    const int tm = blockIdx.x / tiles_n, tn = blockIdx.x - tm * tiles_n;
    const int m0 = tm << 7, n0 = tn << 7;
    const int wr = (wv >> 1) * 64, wc = (wv & 1) * 64;

    v4f acc[4][4] = {};

    for (int k0 = 0; k0 < K; k0 += 64) {
        __syncthreads();
#pragma unroll
        for (int j = 0; j < 4; ++j) {
            const int cb = (wv * 4 + j) * 64;
            const int cl = cb + lane;
            const int row = cl >> 3;
            const int kc = (cl & 7) ^ (row & 7);
            const unsigned short* ga = A + (size_t)(m0 + row) * K + k0 + kc * 8;
            const unsigned short* gb = B + (size_t)(n0 + row) * K + k0 + kc * 8;
            __builtin_amdgcn_global_load_lds(
                (const __attribute__((address_space(1))) unsigned int*)ga,
                (__attribute__((address_space(3))) unsigned int*)(As + cb * 8), 16, 0, 0);
            __builtin_amdgcn_global_load_lds(
                (const __attribute__((address_space(1))) unsigned int*)gb,
                (__attribute__((address_space(3))) unsigned int*)(Bs + cb * 8), 16, 0, 0);
        }
        __syncthreads();
#pragma unroll
        for (int ks = 0; ks < 2; ++ks) {
            v8s af[4], bf[4];
#pragma unroll
            for (int mt = 0; mt < 4; ++mt) {
                const int row = wr + mt * 16 + l16;
                const int ch = row * 8 + ((ks * 4 + quad) ^ (row & 7));
                af[mt] = *(const v8s*)(As + ch * 8);
            }
#pragma unroll
            for (int nt = 0; nt < 4; ++nt) {
                const int row = wc + nt * 16 + l16;
                const int ch = row * 8 + ((ks * 4 + quad) ^ (row & 7));
                bf[nt] = *(const v8s*)(Bs + ch * 8);
            }
#pragma unroll
            for (int mt = 0; mt < 4; ++mt)
#pragma unroll
                for (int nt = 0; nt < 4; ++nt)
                    acc[mt][nt] = __builtin_amdgcn_mfma_f32_16x16x32_bf16(
                        af[mt], bf[nt], acc[mt][nt], 0, 0, 0);
        }
    }
#pragma unroll
    for (int nt = 0; nt < 4; ++nt) {
        const int col = n0 + wc + nt * 16 + l16;
        const float bv = bias[col];
        if (VSPLIT && col >= 2048) {
#pragma unroll
            for (int mt = 0; mt < 4; ++mt) {
                const int rowb = m0 + wr + mt * 16 + quad * 4;
                ushort4 o;
                o.x = f2bf(acc[mt][nt][0] + bv);
                o.y = f2bf(acc[mt][nt][1] + bv);
                o.z = f2bf(acc[mt][nt][2] + bv);
                o.w = f2bf(acc[mt][nt][3] + bv);
                *(ushort4*)(vt + (size_t)(col - 2048) * M + rowb) = o;
            }
        } else {
            const float scl = (VSPLIT && col < 1024) ? QSCALE : 1.0f;
#pragma unroll
            for (int mt = 0; mt < 4; ++mt) {
                const int rowb = m0 + wr + mt * 16 + quad * 4;
#pragma unroll
                for (int r = 0; r < 4; ++r) {
                    if (OUT_F32)
                        ((float*)Cout)[(size_t)(rowb + r) * ldc + col] = acc[mt][nt][r] + bv;
                    else
                        ((unsigned short*)Cout)[(size_t)(rowb + r) * ldc + col] =
                            f2bf((acc[mt][nt][r] + bv) * scl);
                }
            }
        }
    }
}

// ---------------- windowed attention, 32x32x16 MFMA, register-only P ----------------
// (structure proven in round 8: permlane32_swap P redistribution, no P LDS,
//  32 KB LDS, raw v_exp_f32 softmax, Q pre-scaled.)
// ROUND 9 change — T14 async-STAGE split: replace global_load_lds (whose
// barrier drains vmcnt(0) = full L2/HBM latency, no overlap) with reg-staging:
//   ISSUE(kt)->regs a full compute-phase early; ds_write after barrier-1;
//   barrier-2 drains only lgkm (cheap); ISSUE(kt+1) overlaps compute(kt).
// Ordering is carried by real __syncthreads() (write->read crosses a genuine
// barrier — no TBAA hazard, rounds 3-7's lesson). LDS layout and all source
// addresses identical to round 8 (lds_off = cl*8 replicates gload_lds's
// base+lane*16B). Cost: +32 VGPR in flight (est. peak ~150 < the 168 cap of
// launch_bounds(256,3)); spill signal = attn FETCH/WRITE blowup.
__global__ __launch_bounds__(256, 3) void attn_win(const unsigned short* __restrict__ qk,
                                                   const unsigned short* __restrict__ Vt,
                                                   unsigned short* __restrict__ O,
                                                   int W) {
    const int nkt = W >> 7;
    const int tid = threadIdx.x, wv = tid >> 6, lane = tid & 63;
    const int hi = lane >> 5, l32 = lane & 31;

    // block remap (global path): keep the 8 q-blocks of one (window,head) on one XCD
    int wh, qb;
    if (nkt == 8) {
        const int g = blockIdx.x;
        wh = (g >> 6) * 8 + (g & 7);     // window*16+head
        qb = (g >> 3) & 7;
    } else {
        wh = blockIdx.x; qb = 0;
    }
    const int winst = wh >> 4, head = wh & 15;
    const size_t rw = (size_t)winst * W;

    __shared__ unsigned short Ks[128 * 64];     // [key][8 dh-chunks, XOR-swizzled]
    __shared__ unsigned short Vs[64 * 128];     // [dh][16 key-chunks, XOR-swizzled]

    const int irow = qb * 128 + wv * 32 + l32;  // this lane's q-row (window-relative)
    const int thr  = irow - 4 * hi;             // mask: key > irow <=> kx > thr

    // Q frags (B-operand: lane&31 = q-row, k = hi*8+j), 4 k-steps of dh16
    v8s qf[4];
    {
        const size_t qrow = rw + (size_t)irow;
        const unsigned short* qp = qk + qrow * 2048 + head * 64 + hi * 8;
#pragma unroll
        for (int ks = 0; ks < 4; ++ks) qf[ks] = *(const v8s*)(qp + ks * 16);
    }

    // staging: per-thread kt-invariant offsets (same layout as round 8's gload_lds)
    v8s kreg[4], vreg[4];
    size_t kglob[4], vglob[4];
    int lds_off[4];
#pragma unroll
    for (int j = 0; j < 4; ++j) {
        const int cl = (wv * 4 + j) * 64 + lane;
        const int key = cl >> 3, kc = cl & 7;
        kglob[j] = (size_t)key * 2048 + 1024 + head * 64 + ((kc ^ (key & 7)) * 8);
        const int dh = cl >> 4, vc = cl & 15;
        vglob[j] = (size_t)(head * 64 + dh) * 16384 + rw + ((vc ^ (dh & 7)) * 8);
        lds_off[j] = cl * 8;
    }
#define ISSUE_TILE(kt_) do {                                              \
        const size_t kb_ = (rw + (size_t)((kt_) * 128)) * 2048;           \
        const size_t vb_ = (size_t)((kt_) * 128);                         \
        _Pragma("unroll")                                                 \
        for (int j = 0; j < 4; ++j) {                                     \
            kreg[j] = *(const v8s*)(qk + kb_ + kglob[j]);                 \
            vreg[j] = *(const v8s*)(Vt + vb_ + vglob[j]);                 \
        } } while (0)

    ISSUE_TILE(0);

    float rsum = 0.f;
    f32x16 oacc[2] = {};   // O C-layout: col=l32=dh (per 32-group), row r = q-within-32

    for (int kt = 0; kt < nkt; ++kt) {
        __syncthreads();   // all waves done computing kt-1; kt's loads landed (vmcnt drain free)
#pragma unroll
        for (int j = 0; j < 4; ++j) {
            *(v8s*)(Ks + lds_off[j]) = kreg[j];
            *(v8s*)(Vs + lds_off[j]) = vreg[j];
        }
        __syncthreads();   // ds_writes visible to all waves (lgkm-only drain — cheap)
        if (kt + 1 < nkt) ISSUE_TILE(kt + 1);   // HBM/L2 latency hides under compute(kt)

#pragma unroll
        for (int kg = 0; kg < 4; ++kg) {        // 32 keys per group
            // S^T for this key-group (accumulate over dh in 4 k-steps)
            f32x16 s = {};
            const int key0 = kg * 32 + l32;
#pragma unroll
            for (int ks = 0; ks < 4; ++ks) {
                const v8s kf = *(const v8s*)(Ks + key0 * 64
                                             + (((ks << 1) | hi) ^ (key0 & 7)) * 8);
                s = __builtin_amdgcn_mfma_f32_32x32x16_bf16(kf, qf[ks], s, 0, 0, 0);
            }
            // softmax (this lane's 16 of the 32 keys, all for q-row l32)
            const int kb = kt * 128 + kg * 32;
            float e[16];
#pragma unroll
            for (int r = 0; r < 16; ++r) {
                const int kx = kb + (r & 3) + 8 * (r >> 2);   // +4*hi folded into thr
                e[r] = __builtin_amdgcn_exp2f(s[r] + ((kx > thr) ? L2E : 0.0f));
            }
            rsum += (((e[0] + e[1]) + (e[2] + e[3])) + ((e[4] + e[5]) + (e[6] + e[7])))
                  + (((e[8] + e[9]) + (e[10] + e[11])) + ((e[12] + e[13]) + (e[14] + e[15])));
            // pack P to bf16 A-frags in-register (cvt_pk + permlane32_swap) + PV
#pragma unroll
            for (int h = 0; h < 2; ++h) {       // 16-key subgroup
                uint32_t wA = cvt_pk_bf16(e[8 * h + 0], e[8 * h + 1]);
                uint32_t wB = cvt_pk_bf16(e[8 * h + 4], e[8 * h + 5]);
                uint32_t wC = cvt_pk_bf16(e[8 * h + 2], e[8 * h + 3]);
                uint32_t wD = cvt_pk_bf16(e[8 * h + 6], e[8 * h + 7]);
                asm("v_permlane32_swap_b32 %0, %1" : "+v"(wA), "+v"(wB));
                asm("v_permlane32_swap_b32 %0, %1" : "+v"(wC), "+v"(wD));
                union { uint32_t u[4]; v8s s8; } pa;
                pa.u[0] = wA; pa.u[1] = wC; pa.u[2] = wB; pa.u[3] = wD;
                const int c0 = kg * 4 + h * 2 + hi;   // 16-chunk index into 128 keys
#pragma unroll
                for (int dhg = 0; dhg < 2; ++dhg) {
                    const int dh = dhg * 32 + l32;
                    const v8s vf = *(const v8s*)(Vs + dh * 128 + ((c0 ^ (dh & 7))) * 8);
                    oacc[dhg] = __builtin_amdgcn_mfma_f32_32x32x16_bf16(
                        pa.s8, vf, oacc[dhg], 0, 0, 0);
                }
            }
        }
    }
#undef ISSUE_TILE

    // rsum: lane has the partial for q=l32 over its hi-half keys; combine halves
    const float tot = rsum + __shfl_xor(rsum, 32);
    const float inv = 1.0f / tot;
#pragma unroll
    for (int r = 0; r < 16; ++r) {
        const int q32 = (r & 3) + 8 * (r >> 2) + 4 * hi;   // q-row within 32
        const float invr = __shfl(inv, q32 + (hi << 5));   // inv lives on lane q32 (both halves)
        const size_t row = rw + (size_t)(qb * 128 + wv * 32 + q32);
#pragma unroll
        for (int dhg = 0; dhg < 2; ++dhg)
            O[row * 1024 + head * 64 + dhg * 32 + l32] = f2bf(oacc[dhg][r] * invr);
    }
}

// ---------------- launcher ----------------
extern "C" void kernel_launch(void* const* d_in, const int* in_sizes, int n_in,
                              void* d_out, int out_size, void* d_ws, size_t ws_size,
                              hipStream_t stream) {
    const float* lqs    = (const float*)d_in[0];
    const float* gqs    = (const float*)d_in[1];
    const float* wl_in  = (const float*)d_in[2];
    const float* bl_in  = (const float*)d_in[3];
    const float* wl_out = (const float*)d_in[4];
    const float* bl_out = (const float*)d_in[5];
    const float* wg_in  = (const float*)d_in[6];
    const float* bg_in  = (const float*)d_in[7];
    const float* wg_out = (const float*)d_in[8];
    const float* bg_out = (const float*)d_in[9];

    char* ws = (char*)d_ws;                                       // total 176,160,768 B
    unsigned short* Xbf    = (unsigned short*)(ws);               // 33,554,432
    unsigned short* Obf    = (unsigned short*)(ws + 33554432);    // 33,554,432
    unsigned short* Winbf  = (unsigned short*)(ws + 67108864);    //  6,291,456
    unsigned short* Woutbf = (unsigned short*)(ws + 73400320);    //  2,097,152
    unsigned short* QKbf   = (unsigned short*)(ws + 75497472);    // 67,108,864  [R][2048]
    unsigned short* Vtbf   = (unsigned short*)(ws + 142606336);   // 33,554,432  [1024][R]

    const int R = 4 * 4096;   // 16384 rows (windows tile S contiguously)
    const int D = 1024;

    for (int path = 0; path < 2; ++path) {
        const float* x     = path == 0 ? lqs : gqs;
        const float* w_in  = path == 0 ? wl_in : wg_in;
        const float* b_in  = path == 0 ? bl_in : bg_in;
        const float* w_out = path == 0 ? wl_out : wg_out;
        const float* b_out = path == 0 ? bl_out : bg_out;
        const int W        = path == 0 ? 128 : 1024;
        float* outp = (float*)d_out + (size_t)path * R * D;

        hipLaunchKernelGGL(cast_f32_bf16, dim3(4096), dim3(256), 0, stream, x, Xbf, R * D);
        hipLaunchKernelGGL(cast_f32_bf16, dim3(3072), dim3(256), 0, stream, w_in, Winbf, 3 * D * D);
        hipLaunchKernelGGL(cast_f32_bf16, dim3(1024), dim3(256), 0, stream, w_out, Woutbf, D * D);
        // QKV projection: Q|K row-major (ldc=2048, Q pre-scaled), V transposed into Vtbf
        hipLaunchKernelGGL((gemm_nt<false, true>), dim3(128 * 24), dim3(256), 0, stream,
                           Xbf, Winbf, b_in, (void*)QKbf, Vtbf, R, 3 * D, D, 2048);
        hipLaunchKernelGGL(attn_win, dim3(2048), dim3(256), 0, stream, QKbf, Vtbf, Obf, W);
        // output projection -> fp32 d_out
        hipLaunchKernelGGL((gemm_nt<true, false>), dim3(128 * 8), dim3(256), 0, stream,
                           Obf, Woutbf, b_out, (void*)outp, (unsigned short*)nullptr,
                           R, D, D, 1024);
    }
}